// Round 4
// baseline (716.440 us; speedup 1.0000x reference)
//
#include <hip/hip_runtime.h>

#define NEG_SLOPE 0.2f
#define EPS_ 1e-9f

typedef __attribute__((ext_vector_type(8))) short short8v;
typedef __attribute__((ext_vector_type(4))) float f32x4;

__device__ __forceinline__ float bf2f(unsigned short u) {
    return __uint_as_float(((unsigned)u) << 16);
}
__device__ __forceinline__ unsigned short f2bf(float f) {
    unsigned u = __float_as_uint(f);
    u = u + 0x7FFFu + ((u >> 16) & 1u);   // round-to-nearest-even
    return (unsigned short)(u >> 16);
}

// ------------------- CSR build -------------------
__global__ void hist_kernel(const int* __restrict__ src, int* __restrict__ cnt, int E) {
    int i = blockIdx.x * blockDim.x + threadIdx.x;
    if (i < E) atomicAdd(&cnt[src[i]], 1);
}

__global__ __launch_bounds__(256) void scan1_kernel(const int* __restrict__ cnt,
        int* __restrict__ locpre, int* __restrict__ blocksum, int n) {
    int t = threadIdx.x;
    int lane = t & 63, wid = t >> 6;
    int base = blockIdx.x * 1024 + t * 4;
    int4 v = {0, 0, 0, 0};
    if (base + 3 < n) {
        v = *(const int4*)(cnt + base);
    } else {
        if (base + 0 < n) v.x = cnt[base + 0];
        if (base + 1 < n) v.y = cnt[base + 1];
        if (base + 2 < n) v.z = cnt[base + 2];
        if (base + 3 < n) v.w = cnt[base + 3];
    }
    int s = v.x + v.y + v.z + v.w;
    int incl = s;
    for (int off = 1; off < 64; off <<= 1) {
        int u = __shfl_up(incl, off);
        if (lane >= off) incl += u;
    }
    __shared__ int ws[4];
    if (lane == 63) ws[wid] = incl;
    __syncthreads();
    int woff = 0;
    for (int i = 0; i < wid; ++i) woff += ws[i];
    int excl = incl - s + woff;
    int4 o;
    o.x = excl; o.y = excl + v.x; o.z = o.y + v.y; o.w = o.z + v.z;
    if (base + 3 < n) {
        *(int4*)(locpre + base) = o;
    } else {
        if (base + 0 < n) locpre[base + 0] = o.x;
        if (base + 1 < n) locpre[base + 1] = o.y;
        if (base + 2 < n) locpre[base + 2] = o.z;
        if (base + 3 < n) locpre[base + 3] = o.w;
    }
    if (t == 255) blocksum[blockIdx.x] = excl + s;
}

__global__ __launch_bounds__(64) void scan2_kernel(int* __restrict__ blocksum, int nb) {
    int lane = threadIdx.x;
    int carry = 0;
    for (int base = 0; base < nb; base += 64) {
        int v = (base + lane < nb) ? blocksum[base + lane] : 0;
        int incl = v;
        for (int off = 1; off < 64; off <<= 1) {
            int u = __shfl_up(incl, off);
            if (lane >= off) incl += u;
        }
        int tot = __shfl(incl, 63);
        if (base + lane < nb) blocksum[base + lane] = incl - v + carry;
        carry += tot;
    }
}

__global__ __launch_bounds__(256) void scan3_kernel(const int* __restrict__ locpre,
        const int* __restrict__ blocksum, int* __restrict__ row_ptr,
        int* __restrict__ cursor, int n, int total) {
    int base = blockIdx.x * 1024 + threadIdx.x * 4;
    int off = blocksum[blockIdx.x];
    if (base + 3 < n) {
        int4 v = *(const int4*)(locpre + base);
        v.x += off; v.y += off; v.z += off; v.w += off;
        *(int4*)(row_ptr + base) = v;
        *(int4*)(cursor + base) = v;
    } else {
        for (int i = 0; i < 4; ++i) {
            if (base + i < n) {
                int v = locpre[base + i] + off;
                row_ptr[base + i] = v;
                cursor[base + i] = v;
            }
        }
    }
    if (blockIdx.x == 0 && threadIdx.x == 0) row_ptr[n] = total;
}

__global__ void scatter_kernel(const int* __restrict__ src, const int* __restrict__ dst,
        int* __restrict__ cursor, int* __restrict__ colv, int E) {
    int i = blockIdx.x * blockDim.x + threadIdx.x;
    if (i < E) {
        int p = atomicAdd(&cursor[src[i]], 1);
        colv[p] = dst[i];
    }
}

// ------------------- W transpose + bf16 convert -------------------
__global__ void wt_kernel(const float* __restrict__ W, short* __restrict__ Wt) {
    int nn = blockIdx.x, k = threadIdx.x;
    Wt[nn * 256 + k] = (short)f2bf(W[k * 256 + nn]);   // Wt[n][k] = W[k][n]
}

// ------------------- GEMM: h' = h @ W (bf16 MFMA) + fused alpha dot-products ----
// Epilogue computes asrc[row]=h'.a[:256], adst[row]=h'.a[256:] from accumulators
// (each wave holds full 256-col rows), removing the separate alpha kernel + re-read.
template<bool IN_BF16>
__global__ __launch_bounds__(256) void gemm_kernel(const void* __restrict__ hin,
        const short* __restrict__ Wt, short* __restrict__ hp,
        const float* __restrict__ af, float* __restrict__ asrc,
        float* __restrict__ adst, int M) {
    __shared__ short As[64 * 40];    // 64 rows x 32 k, pad to 40
    __shared__ short Bt[256 * 40];   // 256 n-rows x 32 k, pad to 40
    int tid = threadIdx.x;
    int lane = tid & 63, w = tid >> 6;
    int m0 = blockIdx.x * 64;

    f32x4 acc[16];
#pragma unroll
    for (int t = 0; t < 16; ++t) acc[t] = (f32x4){0.f, 0.f, 0.f, 0.f};

    int ar = tid >> 2;          // 0..63
    int ac = (tid & 3) * 8;     // 0,8,16,24
    int agrow = m0 + ar;

    for (int kk = 0; kk < 256; kk += 32) {
        short8v av = (short8v){0,0,0,0,0,0,0,0};
        if constexpr (IN_BF16) {
            if (agrow < M)
                av = *(const short8v*)((const short*)hin + (size_t)agrow * 256 + kk + ac);
        } else {
            if (agrow < M) {
                const float* s = (const float*)hin + (size_t)agrow * 256 + kk + ac;
                float4 v0 = *(const float4*)s;
                float4 v1 = *(const float4*)(s + 4);
                av[0] = (short)f2bf(v0.x); av[1] = (short)f2bf(v0.y);
                av[2] = (short)f2bf(v0.z); av[3] = (short)f2bf(v0.w);
                av[4] = (short)f2bf(v1.x); av[5] = (short)f2bf(v1.y);
                av[6] = (short)f2bf(v1.z); av[7] = (short)f2bf(v1.w);
            }
        }
        *(short8v*)&As[ar * 40 + ac] = av;
        {
            const short* s = Wt + (size_t)tid * 256 + kk;
#pragma unroll
            for (int i = 0; i < 4; ++i)
                *(short8v*)&Bt[tid * 40 + i * 8] = *(const short8v*)(s + i * 8);
        }
        __syncthreads();
        short8v a = *(const short8v*)&As[(16 * w + (lane & 15)) * 40 + (lane >> 4) * 8];
#pragma unroll
        for (int t = 0; t < 16; ++t) {
            short8v b = *(const short8v*)&Bt[(16 * t + (lane & 15)) * 40 + (lane >> 4) * 8];
            acc[t] = __builtin_amdgcn_mfma_f32_16x16x32_bf16(a, b, acc[t], 0, 0, 0);
        }
        __syncthreads();
    }
    int r0 = 16 * w + (lane >> 4) * 4;
    int c0 = lane & 15;
    // stage the two a-slices this lane needs (af is tiny and cache-hot)
    float a_s[16], a_d[16];
#pragma unroll
    for (int t = 0; t < 16; ++t) {
        a_s[t] = af[16 * t + c0];
        a_d[t] = af[256 + 16 * t + c0];
    }
#pragma unroll
    for (int j = 0; j < 4; ++j) {
        int grow = m0 + r0 + j;
        float ssrc = 0.f, sdst = 0.f;
#pragma unroll
        for (int t = 0; t < 16; ++t) {
            float cv = acc[t][j];
            ssrc = fmaf(cv, a_s[t], ssrc);
            sdst = fmaf(cv, a_d[t], sdst);
            if (grow < M) hp[(size_t)grow * 256 + 16 * t + c0] = (short)f2bf(cv);
        }
        // reduce across the 16 lanes (c0 = 0..15) holding this row
        for (int off = 1; off < 16; off <<= 1) {
            ssrc += __shfl_xor(ssrc, off);
            sdst += __shfl_xor(sdst, off);
        }
        if (c0 == 0 && grow < M) { asrc[grow] = ssrc; adst[grow] = sdst; }
    }
}

// ------------------- aggregation: one wave per node, scalar-uniform inner loop ----
// readfirstlane(node) makes the edge loop provably wave-uniform: colv[e+k] and
// adst[j] become s_loads (SMEM pipe), the hp row-gather becomes saddr-form
// global_load with a loop-invariant lane offset, and no ds_bpermute remains
// (R3: per-edge __shfl before each gather serialized load issue on the DS pipe).
template<bool OUT_BF16>
__global__ __launch_bounds__(256) void aggregate_kernel(const int* __restrict__ row_ptr,
        const int* __restrict__ colv, const float* __restrict__ asrc,
        const float* __restrict__ adst, const unsigned short* __restrict__ hp,
        void* __restrict__ outp, int n) {
    int node = (blockIdx.x * blockDim.x + threadIdx.x) >> 6;
    int lane = threadIdx.x & 63;
    if (node >= n) return;
    node = __builtin_amdgcn_readfirstlane(node);   // provably uniform -> scalar chain
    int beg = row_ptr[node], end = row_ptr[node + 1];
    float ai = asrc[node];
    const ushort4* __restrict__ hpv = (const ushort4*)hp;   // row j at hpv[j*64+lane]
    float acc0 = 0.f, acc1 = 0.f, acc2 = 0.f, acc3 = 0.f, rs = 0.f;
    for (int e = beg; e < end; e += 16) {
        int m = end - e;   // uniform
        int js[16]; float ds[16]; ushort4 qs[16];
#pragma unroll
        for (int k = 0; k < 16; ++k)
            if (k < m) { js[k] = colv[e + k]; ds[k] = adst[js[k]]; }
#pragma unroll
        for (int k = 0; k < 16; ++k)
            if (k < m) qs[k] = hpv[(size_t)js[k] * 64 + lane];
#pragma unroll
        for (int k = 0; k < 16; ++k)
            if (k < m) {
                float x = ai + ds[k];
                float lr = fmaxf(x, NEG_SLOPE * x);   // leaky_relu
                float wk = __expf(-lr);               // uniform, redundant per lane
                ushort4 q = qs[k];
                acc0 = fmaf(wk, bf2f(q.x), acc0);
                acc1 = fmaf(wk, bf2f(q.y), acc1);
                acc2 = fmaf(wk, bf2f(q.z), acc2);
                acc3 = fmaf(wk, bf2f(q.w), acc3);
                rs += wk;
            }
    }
    float inv = 1.f / (rs + EPS_);
    float v0 = acc0 * inv, v1 = acc1 * inv, v2 = acc2 * inv, v3 = acc3 * inv;
    v0 = v0 > 0.f ? v0 : __expf(v0) - 1.f;
    v1 = v1 > 0.f ? v1 : __expf(v1) - 1.f;
    v2 = v2 > 0.f ? v2 : __expf(v2) - 1.f;
    v3 = v3 > 0.f ? v3 : __expf(v3) - 1.f;
    if constexpr (OUT_BF16) {
        ushort4 o;
        o.x = f2bf(v0); o.y = f2bf(v1); o.z = f2bf(v2); o.w = f2bf(v3);
        *(ushort4*)((unsigned short*)outp + (size_t)node * 256 + lane * 4) = o;
    } else {
        float4 o = {v0, v1, v2, v3};
        *(float4*)((float*)outp + (size_t)node * 256 + lane * 4) = o;
    }
}

extern "C" void kernel_launch(void* const* d_in, const int* in_sizes, int n_in,
                              void* d_out, int out_size, void* d_ws, size_t ws_size,
                              hipStream_t stream) {
    const float* sr_emb = (const float*)d_in[0];
    const float* tg_emb = (const float*)d_in[1];
    const float* W1 = (const float*)d_in[2];
    const float* a1 = (const float*)d_in[3];
    const float* W2 = (const float*)d_in[4];
    const float* a2 = (const float*)d_in[5];
    const int* adj_sr = (const int*)d_in[6];
    const int* adj_tg = (const int*)d_in[7];
    int N = in_sizes[0] / 256;
    int E = in_sizes[6] / 2;

    char* p = (char*)d_ws;
    auto alloc = [&](size_t bytes) -> void* {
        void* r = (void*)p;
        p += (bytes + 255) & ~(size_t)255;
        return r;
    };
    int nb = (N + 1023) / 1024;
    int* cnt      = (int*)alloc((size_t)N * 4);
    int* row_ptr  = (int*)alloc((size_t)(N + 1) * 4);
    int* cursor   = (int*)alloc((size_t)N * 4);
    int* locpre   = (int*)alloc((size_t)N * 4);
    int* blocksum = (int*)alloc((size_t)nb * 4);
    int* colv     = (int*)alloc((size_t)E * 4);
    short* Wt1    = (short*)alloc(256 * 256 * 2);
    short* Wt2    = (short*)alloc(256 * 256 * 2);
    short* hp     = (short*)alloc((size_t)N * 256 * 2);
    float* asrc   = (float*)alloc((size_t)N * 4);
    float* adst   = (float*)alloc((size_t)N * 4);
    short* tmp    = (short*)alloc((size_t)N * 256 * 2);

    wt_kernel<<<256, 256, 0, stream>>>(W1, Wt1);
    wt_kernel<<<256, 256, 0, stream>>>(W2, Wt2);

    int gemm_grid = (N + 63) / 64;
    int nw_grid = (N + 3) / 4;      // one wave per node, 4 waves/block
    int e_grid = (E + 255) / 256;

    for (int g = 0; g < 2; ++g) {
        const int* srcv = (g == 0 ? adj_sr : adj_tg);
        const int* dstv = srcv + E;
        const float* emb = (g == 0 ? sr_emb : tg_emb);
        float* outg = (float*)d_out + (size_t)g * N * 256;

        hipMemsetAsync(cnt, 0, (size_t)N * 4, stream);
        hist_kernel<<<e_grid, 256, 0, stream>>>(srcv, cnt, E);
        scan1_kernel<<<nb, 256, 0, stream>>>(cnt, locpre, blocksum, N);
        scan2_kernel<<<1, 64, 0, stream>>>(blocksum, nb);
        scan3_kernel<<<nb, 256, 0, stream>>>(locpre, blocksum, row_ptr, cursor, N, E);
        scatter_kernel<<<e_grid, 256, 0, stream>>>(srcv, dstv, cursor, colv, E);

        // layer 1: f32 input -> bf16 tmp (alpha fused into gemm epilogue)
        gemm_kernel<false><<<gemm_grid, 256, 0, stream>>>(emb, Wt1, hp, a1, asrc, adst, N);
        aggregate_kernel<true><<<nw_grid, 256, 0, stream>>>(row_ptr, colv, asrc, adst,
                (const unsigned short*)hp, tmp, N);
        // layer 2: bf16 input -> f32 out
        gemm_kernel<true><<<gemm_grid, 256, 0, stream>>>(tmp, Wt2, hp, a2, asrc, adst, N);
        aggregate_kernel<false><<<nw_grid, 256, 0, stream>>>(row_ptr, colv, asrc, adst,
                (const unsigned short*)hp, outg, N);
    }
}

// Round 5
// 636.569 us; speedup vs baseline: 1.1255x; 1.1255x over previous
//
#include <hip/hip_runtime.h>

#define NEG_SLOPE 0.2f
#define EPS_ 1e-9f

typedef __attribute__((ext_vector_type(8))) short short8v;
typedef __attribute__((ext_vector_type(4))) float f32x4;

__device__ __forceinline__ float bf2f(unsigned short u) {
    return __uint_as_float(((unsigned)u) << 16);
}
__device__ __forceinline__ unsigned short f2bf(float f) {
    unsigned u = __float_as_uint(f);
    u = u + 0x7FFFu + ((u >> 16) & 1u);   // round-to-nearest-even
    return (unsigned short)(u >> 16);
}

// ------------------- CSR build -------------------
__global__ void hist_kernel(const int* __restrict__ src, int* __restrict__ cnt, int E) {
    int i = blockIdx.x * blockDim.x + threadIdx.x;
    if (i < E) atomicAdd(&cnt[src[i]], 1);
}

__global__ __launch_bounds__(256) void scan1_kernel(const int* __restrict__ cnt,
        int* __restrict__ locpre, int* __restrict__ blocksum, int n) {
    int t = threadIdx.x;
    int lane = t & 63, wid = t >> 6;
    int base = blockIdx.x * 1024 + t * 4;
    int4 v = {0, 0, 0, 0};
    if (base + 3 < n) {
        v = *(const int4*)(cnt + base);
    } else {
        if (base + 0 < n) v.x = cnt[base + 0];
        if (base + 1 < n) v.y = cnt[base + 1];
        if (base + 2 < n) v.z = cnt[base + 2];
        if (base + 3 < n) v.w = cnt[base + 3];
    }
    int s = v.x + v.y + v.z + v.w;
    int incl = s;
    for (int off = 1; off < 64; off <<= 1) {
        int u = __shfl_up(incl, off);
        if (lane >= off) incl += u;
    }
    __shared__ int ws[4];
    if (lane == 63) ws[wid] = incl;
    __syncthreads();
    int woff = 0;
    for (int i = 0; i < wid; ++i) woff += ws[i];
    int excl = incl - s + woff;
    int4 o;
    o.x = excl; o.y = excl + v.x; o.z = o.y + v.y; o.w = o.z + v.z;
    if (base + 3 < n) {
        *(int4*)(locpre + base) = o;
    } else {
        if (base + 0 < n) locpre[base + 0] = o.x;
        if (base + 1 < n) locpre[base + 1] = o.y;
        if (base + 2 < n) locpre[base + 2] = o.z;
        if (base + 3 < n) locpre[base + 3] = o.w;
    }
    if (t == 255) blocksum[blockIdx.x] = excl + s;
}

__global__ __launch_bounds__(64) void scan2_kernel(int* __restrict__ blocksum, int nb) {
    int lane = threadIdx.x;
    int carry = 0;
    for (int base = 0; base < nb; base += 64) {
        int v = (base + lane < nb) ? blocksum[base + lane] : 0;
        int incl = v;
        for (int off = 1; off < 64; off <<= 1) {
            int u = __shfl_up(incl, off);
            if (lane >= off) incl += u;
        }
        int tot = __shfl(incl, 63);
        if (base + lane < nb) blocksum[base + lane] = incl - v + carry;
        carry += tot;
    }
}

__global__ __launch_bounds__(256) void scan3_kernel(const int* __restrict__ locpre,
        const int* __restrict__ blocksum, int* __restrict__ row_ptr,
        int* __restrict__ cursor, int n, int total) {
    int base = blockIdx.x * 1024 + threadIdx.x * 4;
    int off = blocksum[blockIdx.x];
    if (base + 3 < n) {
        int4 v = *(const int4*)(locpre + base);
        v.x += off; v.y += off; v.z += off; v.w += off;
        *(int4*)(row_ptr + base) = v;
        *(int4*)(cursor + base) = v;
    } else {
        for (int i = 0; i < 4; ++i) {
            if (base + i < n) {
                int v = locpre[base + i] + off;
                row_ptr[base + i] = v;
                cursor[base + i] = v;
            }
        }
    }
    if (blockIdx.x == 0 && threadIdx.x == 0) row_ptr[n] = total;
}

// scatter also records src per CSR slot (needed by ew_kernel)
__global__ void scatter_kernel(const int* __restrict__ src, const int* __restrict__ dst,
        int* __restrict__ cursor, int* __restrict__ colv, int* __restrict__ srce, int E) {
    int i = blockIdx.x * blockDim.x + threadIdx.x;
    if (i < E) {
        int s = src[i];
        int p = atomicAdd(&cursor[s], 1);
        colv[p] = dst[i];
        srce[p] = s;
    }
}

// ------------------- per-edge weights, CSR order -------------------
__global__ __launch_bounds__(256) void ew_kernel(const int* __restrict__ srce,
        const int* __restrict__ colv, const float* __restrict__ asrc,
        const float* __restrict__ adst, float* __restrict__ ew, int E) {
    int i = blockIdx.x * blockDim.x + threadIdx.x;
    if (i < E) {
        float x = asrc[srce[i]] + adst[colv[i]];
        float lr = fmaxf(x, NEG_SLOPE * x);   // leaky_relu
        ew[i] = __expf(-lr);
    }
}

// ------------------- W transpose + bf16 convert -------------------
__global__ void wt_kernel(const float* __restrict__ W, short* __restrict__ Wt) {
    int nn = blockIdx.x, k = threadIdx.x;
    Wt[nn * 256 + k] = (short)f2bf(W[k * 256 + nn]);   // Wt[n][k] = W[k][n]
}

// ------------------- GEMM: h' = h @ W (bf16 MFMA) + fused alpha dot-products ----
template<bool IN_BF16>
__global__ __launch_bounds__(256) void gemm_kernel(const void* __restrict__ hin,
        const short* __restrict__ Wt, short* __restrict__ hp,
        const float* __restrict__ af, float* __restrict__ asrc,
        float* __restrict__ adst, int M) {
    __shared__ short As[64 * 40];    // 64 rows x 32 k, pad to 40
    __shared__ short Bt[256 * 40];   // 256 n-rows x 32 k, pad to 40
    int tid = threadIdx.x;
    int lane = tid & 63, w = tid >> 6;
    int m0 = blockIdx.x * 64;

    f32x4 acc[16];
#pragma unroll
    for (int t = 0; t < 16; ++t) acc[t] = (f32x4){0.f, 0.f, 0.f, 0.f};

    int ar = tid >> 2;          // 0..63
    int ac = (tid & 3) * 8;     // 0,8,16,24
    int agrow = m0 + ar;

    for (int kk = 0; kk < 256; kk += 32) {
        short8v av = (short8v){0,0,0,0,0,0,0,0};
        if constexpr (IN_BF16) {
            if (agrow < M)
                av = *(const short8v*)((const short*)hin + (size_t)agrow * 256 + kk + ac);
        } else {
            if (agrow < M) {
                const float* s = (const float*)hin + (size_t)agrow * 256 + kk + ac;
                float4 v0 = *(const float4*)s;
                float4 v1 = *(const float4*)(s + 4);
                av[0] = (short)f2bf(v0.x); av[1] = (short)f2bf(v0.y);
                av[2] = (short)f2bf(v0.z); av[3] = (short)f2bf(v0.w);
                av[4] = (short)f2bf(v1.x); av[5] = (short)f2bf(v1.y);
                av[6] = (short)f2bf(v1.z); av[7] = (short)f2bf(v1.w);
            }
        }
        *(short8v*)&As[ar * 40 + ac] = av;
        {
            const short* s = Wt + (size_t)tid * 256 + kk;
#pragma unroll
            for (int i = 0; i < 4; ++i)
                *(short8v*)&Bt[tid * 40 + i * 8] = *(const short8v*)(s + i * 8);
        }
        __syncthreads();
        short8v a = *(const short8v*)&As[(16 * w + (lane & 15)) * 40 + (lane >> 4) * 8];
#pragma unroll
        for (int t = 0; t < 16; ++t) {
            short8v b = *(const short8v*)&Bt[(16 * t + (lane & 15)) * 40 + (lane >> 4) * 8];
            acc[t] = __builtin_amdgcn_mfma_f32_16x16x32_bf16(a, b, acc[t], 0, 0, 0);
        }
        __syncthreads();
    }
    int r0 = 16 * w + (lane >> 4) * 4;
    int c0 = lane & 15;
    float a_s[16], a_d[16];
#pragma unroll
    for (int t = 0; t < 16; ++t) {
        a_s[t] = af[16 * t + c0];
        a_d[t] = af[256 + 16 * t + c0];
    }
#pragma unroll
    for (int j = 0; j < 4; ++j) {
        int grow = m0 + r0 + j;
        float ssrc = 0.f, sdst = 0.f;
#pragma unroll
        for (int t = 0; t < 16; ++t) {
            float cv = acc[t][j];
            ssrc = fmaf(cv, a_s[t], ssrc);
            sdst = fmaf(cv, a_d[t], sdst);
            if (grow < M) hp[(size_t)grow * 256 + 16 * t + c0] = (short)f2bf(cv);
        }
        for (int off = 1; off < 16; off <<= 1) {
            ssrc += __shfl_xor(ssrc, off);
            sdst += __shfl_xor(sdst, off);
        }
        if (c0 == 0 && grow < M) { asrc[grow] = ssrc; adst[grow] = sdst; }
    }
}

// ------------------- aggregation: one wave per node -------------------
// Inner loop has ZERO cross-lane ops and zero scalar-load chains (R3/R4 lessons):
// colv/ew come in as uniform-address vector loads (HW broadcast, vmcnt-queued),
// the 16 row-gathers issue back-to-back dependent only on the j-block, and
// weights are precomputed (ew_kernel) so consume is pure FMA.
#define GATH(qq, jj) qq = hpv[(size_t)(jj) * 64 + lane];
#define CONS(qq, ww) { acc0 = fmaf(ww, bf2f(qq.x), acc0); acc1 = fmaf(ww, bf2f(qq.y), acc1); \
                       acc2 = fmaf(ww, bf2f(qq.z), acc2); acc3 = fmaf(ww, bf2f(qq.w), acc3); \
                       rs += ww; }

template<bool OUT_BF16>
__global__ __launch_bounds__(256) void aggregate_kernel(const int* __restrict__ row_ptr,
        const int* __restrict__ colv, const float* __restrict__ ew,
        const unsigned short* __restrict__ hp, void* __restrict__ outp, int n) {
    int node = (blockIdx.x * blockDim.x + threadIdx.x) >> 6;
    int lane = threadIdx.x & 63;
    if (node >= n) return;
    int beg = row_ptr[node], end = row_ptr[node + 1];
    const ushort4* __restrict__ hpv = (const ushort4*)hp;   // row j at hpv[j*64+lane]
    float acc0 = 0.f, acc1 = 0.f, acc2 = 0.f, acc3 = 0.f, rs = 0.f;
    int e = beg;
    for (; e + 16 <= end; e += 16) {   // full chunks: no guards at all
        int4 j0 = *(const int4*)(colv + e);
        int4 j1 = *(const int4*)(colv + e + 4);
        int4 j2 = *(const int4*)(colv + e + 8);
        int4 j3 = *(const int4*)(colv + e + 12);
        float4 w0 = *(const float4*)(ew + e);
        float4 w1 = *(const float4*)(ew + e + 4);
        float4 w2 = *(const float4*)(ew + e + 8);
        float4 w3 = *(const float4*)(ew + e + 12);
        ushort4 q0, q1, q2, q3, q4, q5, q6, q7, q8, q9, qa, qb, qc, qd, qe, qf;
        GATH(q0, j0.x) GATH(q1, j0.y) GATH(q2, j0.z) GATH(q3, j0.w)
        GATH(q4, j1.x) GATH(q5, j1.y) GATH(q6, j1.z) GATH(q7, j1.w)
        GATH(q8, j2.x) GATH(q9, j2.y) GATH(qa, j2.z) GATH(qb, j2.w)
        GATH(qc, j3.x) GATH(qd, j3.y) GATH(qe, j3.z) GATH(qf, j3.w)
        CONS(q0, w0.x) CONS(q1, w0.y) CONS(q2, w0.z) CONS(q3, w0.w)
        CONS(q4, w1.x) CONS(q5, w1.y) CONS(q6, w1.z) CONS(q7, w1.w)
        CONS(q8, w2.x) CONS(q9, w2.y) CONS(qa, w2.z) CONS(qb, w2.w)
        CONS(qc, w3.x) CONS(qd, w3.y) CONS(qe, w3.z) CONS(qf, w3.w)
    }
    if (e < end) {                     // tail: colv zero-padded, guard consume only
        int m = end - e;
        int4 j0 = *(const int4*)(colv + e);
        int4 j1 = *(const int4*)(colv + e + 4);
        int4 j2 = *(const int4*)(colv + e + 8);
        int4 j3 = *(const int4*)(colv + e + 12);
        float4 w0 = *(const float4*)(ew + e);
        float4 w1 = *(const float4*)(ew + e + 4);
        float4 w2 = *(const float4*)(ew + e + 8);
        float4 w3 = *(const float4*)(ew + e + 12);
        ushort4 q0, q1, q2, q3, q4, q5, q6, q7, q8, q9, qa, qb, qc, qd, qe, qf;
        GATH(q0, j0.x) GATH(q1, j0.y) GATH(q2, j0.z) GATH(q3, j0.w)
        GATH(q4, j1.x) GATH(q5, j1.y) GATH(q6, j1.z) GATH(q7, j1.w)
        GATH(q8, j2.x) GATH(q9, j2.y) GATH(qa, j2.z) GATH(qb, j2.w)
        GATH(qc, j3.x) GATH(qd, j3.y) GATH(qe, j3.z) GATH(qf, j3.w)
        CONS(q0, w0.x)
        if (m > 1)  CONS(q1, w0.y)
        if (m > 2)  CONS(q2, w0.z)
        if (m > 3)  CONS(q3, w0.w)
        if (m > 4)  CONS(q4, w1.x)
        if (m > 5)  CONS(q5, w1.y)
        if (m > 6)  CONS(q6, w1.z)
        if (m > 7)  CONS(q7, w1.w)
        if (m > 8)  CONS(q8, w2.x)
        if (m > 9)  CONS(q9, w2.y)
        if (m > 10) CONS(qa, w2.z)
        if (m > 11) CONS(qb, w2.w)
        if (m > 12) CONS(qc, w3.x)
        if (m > 13) CONS(qd, w3.y)
        if (m > 14) CONS(qe, w3.z)
    }
    float inv = 1.f / (rs + EPS_);
    float v0 = acc0 * inv, v1 = acc1 * inv, v2 = acc2 * inv, v3 = acc3 * inv;
    v0 = v0 > 0.f ? v0 : __expf(v0) - 1.f;
    v1 = v1 > 0.f ? v1 : __expf(v1) - 1.f;
    v2 = v2 > 0.f ? v2 : __expf(v2) - 1.f;
    v3 = v3 > 0.f ? v3 : __expf(v3) - 1.f;
    if constexpr (OUT_BF16) {
        ushort4 o;
        o.x = f2bf(v0); o.y = f2bf(v1); o.z = f2bf(v2); o.w = f2bf(v3);
        *(ushort4*)((unsigned short*)outp + (size_t)node * 256 + lane * 4) = o;
    } else {
        float4 o = {v0, v1, v2, v3};
        *(float4*)((float*)outp + (size_t)node * 256 + lane * 4) = o;
    }
}

extern "C" void kernel_launch(void* const* d_in, const int* in_sizes, int n_in,
                              void* d_out, int out_size, void* d_ws, size_t ws_size,
                              hipStream_t stream) {
    const float* sr_emb = (const float*)d_in[0];
    const float* tg_emb = (const float*)d_in[1];
    const float* W1 = (const float*)d_in[2];
    const float* a1 = (const float*)d_in[3];
    const float* W2 = (const float*)d_in[4];
    const float* a2 = (const float*)d_in[5];
    const int* adj_sr = (const int*)d_in[6];
    const int* adj_tg = (const int*)d_in[7];
    int N = in_sizes[0] / 256;
    int E = in_sizes[6] / 2;

    char* p = (char*)d_ws;
    auto alloc = [&](size_t bytes) -> void* {
        void* r = (void*)p;
        p += (bytes + 255) & ~(size_t)255;
        return r;
    };
    int nb = (N + 1023) / 1024;
    int* cnt      = (int*)alloc((size_t)N * 4);
    int* row_ptr  = (int*)alloc((size_t)(N + 1) * 4);
    int* cursor   = (int*)alloc((size_t)N * 4);
    int* locpre   = (int*)alloc((size_t)N * 4);
    int* blocksum = (int*)alloc((size_t)nb * 4);
    int* colv     = (int*)alloc((size_t)(E + 16) * 4);   // +16 zero pad
    int* srce     = (int*)alloc((size_t)E * 4);
    float* ew     = (float*)alloc((size_t)(E + 16) * 4); // +16 pad (unconsumed)
    short* Wt1    = (short*)alloc(256 * 256 * 2);
    short* Wt2    = (short*)alloc(256 * 256 * 2);
    short* hp     = (short*)alloc((size_t)N * 256 * 2);
    float* asrc   = (float*)alloc((size_t)N * 4);
    float* adst   = (float*)alloc((size_t)N * 4);
    short* tmp    = (short*)alloc((size_t)N * 256 * 2);

    wt_kernel<<<256, 256, 0, stream>>>(W1, Wt1);
    wt_kernel<<<256, 256, 0, stream>>>(W2, Wt2);

    int gemm_grid = (N + 63) / 64;
    int nw_grid = (N + 3) / 4;      // one wave per node, 4 waves/block
    int e_grid = (E + 255) / 256;

    for (int g = 0; g < 2; ++g) {
        const int* srcv = (g == 0 ? adj_sr : adj_tg);
        const int* dstv = srcv + E;
        const float* emb = (g == 0 ? sr_emb : tg_emb);
        float* outg = (float*)d_out + (size_t)g * N * 256;

        hipMemsetAsync(cnt, 0, (size_t)N * 4, stream);
        hipMemsetAsync(colv + E, 0, 16 * 4, stream);   // zero pad for tail over-read
        hist_kernel<<<e_grid, 256, 0, stream>>>(srcv, cnt, E);
        scan1_kernel<<<nb, 256, 0, stream>>>(cnt, locpre, blocksum, N);
        scan2_kernel<<<1, 64, 0, stream>>>(blocksum, nb);
        scan3_kernel<<<nb, 256, 0, stream>>>(locpre, blocksum, row_ptr, cursor, N, E);
        scatter_kernel<<<e_grid, 256, 0, stream>>>(srcv, dstv, cursor, colv, srce, E);

        // layer 1: f32 input -> bf16 tmp (alpha fused into gemm epilogue)
        gemm_kernel<false><<<gemm_grid, 256, 0, stream>>>(emb, Wt1, hp, a1, asrc, adst, N);
        ew_kernel<<<e_grid, 256, 0, stream>>>(srce, colv, asrc, adst, ew, E);
        aggregate_kernel<true><<<nw_grid, 256, 0, stream>>>(row_ptr, colv, ew,
                (const unsigned short*)hp, tmp, N);
        // layer 2: bf16 input -> f32 out
        gemm_kernel<true><<<gemm_grid, 256, 0, stream>>>(tmp, Wt2, hp, a2, asrc, adst, N);
        ew_kernel<<<e_grid, 256, 0, stream>>>(srce, colv, asrc, adst, ew, E);
        aggregate_kernel<false><<<nw_grid, 256, 0, stream>>>(row_ptr, colv, ew,
                (const unsigned short*)hp, outg, N);
    }
}